// Round 14
// baseline (295.027 us; speedup 1.0000x reference)
//
#include <hip/hip_runtime.h>
#include <math.h>

// ---------------------------------------------------------------------------
// Phase 1: natural cubic spline coefficients, 3 channels. Single block.
// ---------------------------------------------------------------------------
__global__ void spline_setup(const float* __restrict__ delay_in,
                             const float* __restrict__ raw,
                             double* __restrict__ coef,
                             int* __restrict__ minz,
                             int nf) {
    extern __shared__ double smem[];
    double* xch = smem;           // 3*nf
    double* cp  = xch + 3 * nf;   // nf
    double* kk  = cp + nf;        // 3*nf

    int tid = threadIdx.x;
    if (tid == 0) *minz = 0x7fffffff;

    for (int i = tid; i < nf; i += blockDim.x) {
        double s0 = 1.0 / (1.0 + exp(-(double)raw[2 * i + 0]));
        double s1 = 1.0 / (1.0 + exp(-(double)raw[2 * i + 1]));
        double ss = s0 + s1;
        xch[0 * nf + i] = (double)delay_in[i];
        xch[1 * nf + i] = s0 / ss;
        xch[2 * nf + i] = s1 / ss;
    }
    __syncthreads();

    if (tid == 0) {
        cp[0] = 0.5;
        for (int i = 1; i < nf; ++i) {
            double d = (i == nf - 1) ? 2.0 : 4.0;
            cp[i] = 1.0 / (d - cp[i - 1]);
        }
    }
    __syncthreads();

    if (tid < 3) {
        const double* x = xch + tid * nf;
        double* k = kk + tid * nf;
        double hinv = (double)(nf - 1);
        double prev = 0.0;
        for (int j = 0; j < nf; ++j) {
            double r = 0.0;
            if (j < nf - 1) r += 3.0 * hinv * (x[j + 1] - x[j]);
            if (j > 0)      r += 3.0 * hinv * (x[j] - x[j - 1]);
            double dp = (r - prev) * cp[j];
            k[j] = dp;
            prev = dp;
        }
        for (int j = nf - 2; j >= 0; --j) k[j] = k[j] - cp[j] * k[j + 1];
    }
    __syncthreads();

    int nint = nf - 1;
    double hinv = (double)(nf - 1);
    for (int w = tid; w < 3 * nint; w += blockDim.x) {
        int ch = w / nint;
        int i = w - ch * nint;
        const double* x = xch + ch * nf;
        const double* k = kk + ch * nf;
        double dx3 = 3.0 * (x[i + 1] - x[i]);
        double two_c   = (2.0 * dx3 * hinv - 4.0 * k[i] - 2.0 * k[i + 1]) * hinv;
        double three_d = (-2.0 * dx3 * hinv + 3.0 * (k[i] + k[i + 1])) * hinv * hinv;
        double* C = coef + (size_t)(ch * nint + i) * 4;
        C[0] = x[i];
        C[1] = k[i];
        C[2] = 0.5 * two_c;
        C[3] = three_d * (1.0 / 3.0);
    }
}

// ---------------------------------------------------------------------------
// Phase 2: per-sample spline eval -> {g1, g2, g3, s3} one float4.
// s3 = (t - z - 3) & 2047. Global min z via one atomic per wave.
// Pads [n, nTot) with zeros.
// ---------------------------------------------------------------------------
__global__ void eval_kernel(const double* __restrict__ coef,
                            float4* __restrict__ gx,
                            int* __restrict__ minz,
                            int n, int nTot, int nf) {
    int j = blockIdx.x * blockDim.x + threadIdx.x;
    if (j >= nTot) return;
    if (j >= n) { gx[j] = make_float4(0.f, 0.f, 0.f, 0.f); return; }

    double u = (double)j / (double)(n - 1);
    double nfm1 = (double)(nf - 1);
    int idx = (int)(u * nfm1);
    if (idx > nf - 2) idx = nf - 2;
    if (idx < 0) idx = 0;
    double tknot = (double)idx / nfm1;
    if (u < tknot && idx > 0) {
        idx--; tknot = (double)idx / nfm1;
    } else {
        double tnext = (double)(idx + 1) / nfm1;
        if (u >= tnext && idx < nf - 2) { idx++; tknot = tnext; }
    }
    double f = u - tknot;

    int nint = nf - 1;
    const double* C0 = coef + (size_t)(0 * nint + idx) * 4;
    const double* C1 = coef + (size_t)(1 * nint + idx) * 4;
    const double* C2 = coef + (size_t)(2 * nint + idx) * 4;
    double dly = C0[0] + f * (C0[1] + f * (C0[2] + f * C0[3]));
    double b1d = C1[0] + f * (C1[1] + f * (C1[2] + f * C1[3]));
    double b2d = C2[0] + f * (C2[1] + f * (C2[2] + f * C2[3]));

    double zf = floor(dly);
    int z = (int)zf;
    float alfa = (float)(dly - zf);
    float b1 = (float)b1d, b2 = (float)b2d;
    float g1 = b1 * (1.0f - alfa);
    float g2 = b1 * alfa + b2 * (1.0f - alfa);
    float g3 = b2 * alfa;

    int s3 = (j - z - 3) & 2047;
    gx[j] = make_float4(g1, g2, g3, __uint_as_float((unsigned int)s3));

    int wmin = z;
    #pragma unroll
    for (int o = 32; o > 0; o >>= 1) wmin = min(wmin, __shfl_down(wmin, o, 64));
    if ((threadIdx.x & 63) == 0) atomicMin(minz, wmin);
}

// ---------------------------------------------------------------------------
// Phase 3: producer/consumer, RUNTIME D = min(minz+1, 128) (2-row chunks:
// row0 always full 64 lanes since D >= 65, row1 has D-64 active lanes).
// Serial steps drop from n/64=2048 (R13) to n/D~1298; chain/chunk grows only
// by row1's issue (~30cy) on top of the ~120cy LDS round trip.
// Invariant: every history read of a chunk targets positions < chunk base
// (D <= minz+1). Group = 8 chunks (span = 8D <= 1024 samples).
// Ring: 4 group-slots x 8 chunks x 128 float4 (compile-time strides; only
// t/base arithmetic is runtime). Producer per group: exactly 16 y-offload
// stores (sink-redirected when masked) + 16 global_load_lds (group g+2),
// then counted s_waitcnt vmcnt(32) -> group g+1 resident; loads stay in
// flight across the raw s_barrier (R11/R13-validated).
// buf = 2048 circular + 2 shadow (mirror 0/1) + 2 dummy. Producer reads
// window g-1 while consumer writes window g: distance <= 2*span <= 2048 ok.
// ---------------------------------------------------------------------------
__global__ void __launch_bounds__(128, 1)
scan_kernel(const float4* __restrict__ gx,
            const int* __restrict__ minz,
            const float* __restrict__ exc,
            float* __restrict__ y,
            float* __restrict__ sink,
            int n, int burst) {
    __shared__ float buf[2052];          // 2048 circular + 2 shadow + 2 dummy
    __shared__ float excl[2048];
    __shared__ float4 ring[4 * 1024];    // 4 slots x 8 chunks x 128 = 64 KB

    const int tid = threadIdx.x;
    for (int i = tid; i < 2052; i += 128) buf[i] = 0.0f;
    for (int i = tid; i < 2048; i += 128) excl[i] = (i < burst) ? exc[i] : 0.0f;

    int mz = __builtin_amdgcn_readfirstlane(*minz);
    int D = mz + 1;
    if (D > 128) D = 128;
    const int span = D << 3;             // samples per group (<= 1024)
    const int nC = n / D;                // full chunks
    const int nGF = nC >> 3;             // full groups

#define GLL(gsrc, ldst)                                                       \
    __builtin_amdgcn_global_load_lds(                                         \
        (const __attribute__((address_space(1))) void*)(gsrc),                \
        (__attribute__((address_space(3))) void*)(ldst), 16, 0, 0)

    // ---------------- fallback (never taken here: mz ~ 100, nGF ~ 160) -----
    if (D < 65 || nGF < 3) {
        __syncthreads();
        if (tid < 64) {
            int Df = mz + 1;
            if (Df > 64) Df = 64;
            if (Df < 1) Df = 1;
            for (int base = 0; base < n; base += Df) {
                int t = base + tid;
                bool ok = (tid < Df) && (t < n);
                float4 q = ok ? gx[t] : make_float4(0.f, 0.f, 0.f, 0.f);
                unsigned u = __float_as_uint(q.w) & 2047u;
                float a3 = buf[u], a2 = buf[u + 1], a1 = buf[u + 2];
                float x = (t < burst) ? excl[t & 2047] : 0.0f;
                float y0 = fmaf(q.x, a1, x);
                y0 = fmaf(q.y, a2, y0);
                y0 = fmaf(q.z, a3, y0);
                if (ok) {
                    int w = t & 2047;
                    buf[w] = y0;
                    if (w < 2) buf[2048 + w] = y0;
                    y[t] = y0;
                }
            }
        }
        return;
    }

    // ---------------- prologue: producer fills groups 0,1 ------------------
    if (tid >= 64) {
        int lane = tid - 64;
        #pragma unroll
        for (int c = 0; c < 8; ++c) {
            GLL(gx + c * D + lane, &ring[(c << 7)]);
            GLL(gx + c * D + 64 + lane, &ring[(c << 7) + 64]);
        }
        #pragma unroll
        for (int c = 0; c < 8; ++c) {
            GLL(gx + (8 + c) * D + lane, &ring[1024 + (c << 7)]);
            GLL(gx + (8 + c) * D + 64 + lane, &ring[1024 + (c << 7) + 64]);
        }
    }
    __syncthreads();   // full drain: groups 0,1 resident; buf/excl visible

    for (int g = 0; g < nGF; ++g) {
        if (tid >= 64) {
            // ---------------- producer ----------------
            int lane = tid - 64;
            int gs = (g - 1) * span;               // sample base of group g-1
            int bs = gs & 2047;
            float vals[16];
            #pragma unroll
            for (int k = 0; k < 16; ++k)
                vals[k] = buf[(bs + (k << 6) + lane) & 2047];
            #pragma unroll
            for (int k = 0; k < 16; ++k) {
                int off = (k << 6) + lane;
                bool ok = (g > 0) && (off < span);
                float* dst = ok ? (y + gs + off) : (sink + off);
                *dst = vals[k];                    // exactly 16 stores
            }
            int pb = (g + 2) * span;
            int slot = (g + 2) & 3;
            #pragma unroll
            for (int c = 0; c < 8; ++c) {
                GLL(gx + pb + c * D + lane, &ring[(slot << 10) + (c << 7)]);
                GLL(gx + pb + c * D + 64 + lane, &ring[(slot << 10) + (c << 7) + 64]);
            }
            // counted wait: drains prev group's 32 ops (incl. g+1's loads)
            asm volatile("s_waitcnt vmcnt(32)" ::: "memory");
        } else {
            // ---------------- consumer (pure LDS) ----------------
            const float4* Rp = ring + ((g & 3) << 10);
            int bc = g * span;                     // chunk base (uniform)
            float4 q0 = Rp[tid];
            float4 q1 = Rp[64 + tid];
            #pragma unroll
            for (int c = 0; c < 8; ++c) {
                float4 n0, n1;
                if (c < 7) {
                    n0 = Rp[((c + 1) << 7) + tid];
                    n1 = Rp[((c + 1) << 7) + 64 + tid];
                }
                unsigned u0 = __float_as_uint(q0.w) & 2047u;
                unsigned u1 = __float_as_uint(q1.w) & 2047u;
                float a3 = buf[u0], a2 = buf[u0 + 1], a1 = buf[u0 + 2];
                float b3 = buf[u1], b2 = buf[u1 + 1], b1 = buf[u1 + 2];
                int t0 = bc + tid;
                int t1 = t0 + 64;
                float x0 = 0.0f, x1 = 0.0f;
                if (bc < burst) {                  // uniform; first ~3 groups
                    x0 = (t0 < burst) ? excl[t0 & 2047] : 0.0f;
                    x1 = (t1 < burst) ? excl[t1 & 2047] : 0.0f;
                }
                float y0 = fmaf(q0.x, a1, x0);
                y0 = fmaf(q0.y, a2, y0);
                y0 = fmaf(q0.z, a3, y0);
                float y1 = fmaf(q1.x, b1, x1);
                y1 = fmaf(q1.y, b2, y1);
                y1 = fmaf(q1.z, b3, y1);
                int w0 = t0 & 2047;
                int w1 = t1 & 2047;
                bool ok1 = (64 + tid) < D;         // row0 always on (D>=65)
                buf[w0] = y0;
                buf[ok1 ? w1 : 2050] = y1;
                buf[(w0 < 2) ? 2048 + w0 : 2050] = y0;
                buf[(ok1 && w1 < 2) ? 2048 + w1 : 2051] = y1;
                q0 = n0; q1 = n1; bc += D;
            }
        }
        // raw barrier: producer's g+2 loads stay in flight across it
        asm volatile("s_waitcnt lgkmcnt(0)" ::: "memory");
        __builtin_amdgcn_sched_barrier(0);
        __builtin_amdgcn_s_barrier();
        __builtin_amdgcn_sched_barrier(0);
    }

    __syncthreads();   // drain everything before epilogue

    if (tid >= 64) {
        // offload group nGF-1 (final in buf)
        int lane = tid - 64;
        int gs = (nGF - 1) * span;
        #pragma unroll
        for (int k = 0; k < 16; ++k) {
            int off = (k << 6) + lane;
            if (off < span) y[gs + off] = buf[(gs + off) & 2047];
        }
    } else {
        // tail samples [nGF*span, n): direct-global, masked, serial in-wave
        for (int base = nGF * span; base < n; base += 64) {
            int t = base + tid;
            bool ok = (t < n);
            float4 q = ok ? gx[t] : make_float4(0.f, 0.f, 0.f, 0.f);
            unsigned u = __float_as_uint(q.w) & 2047u;
            float a3 = buf[u], a2 = buf[u + 1], a1 = buf[u + 2];
            float x = (t < burst) ? excl[t & 2047] : 0.0f;
            float y0 = fmaf(q.x, a1, x);
            y0 = fmaf(q.y, a2, y0);
            y0 = fmaf(q.z, a3, y0);
            if (ok) {
                int w = t & 2047;
                buf[w] = y0;
                if (w < 2) buf[2048 + w] = y0;
                y[t] = y0;
            }
        }
    }
#undef GLL
}

// ---------------------------------------------------------------------------
extern "C" void kernel_launch(void* const* d_in, const int* in_sizes, int n_in,
                              void* d_out, int out_size, void* d_ws, size_t ws_size,
                              hipStream_t stream) {
    const float* delay = (const float*)d_in[0];
    const float* raw   = (const float*)d_in[1];
    const float* exc   = (const float*)d_in[2];
    int nf = in_sizes[0];
    int burst = in_sizes[2];
    if (burst > 2048) burst = 2048;
    int n = out_size;
    int nTot = n + 4096;   // pad covers producer prefetch overshoot (~2 spans + chunk)

    char* ws = (char*)d_ws;
    size_t coefBytes = (size_t)3 * (nf - 1) * 4 * sizeof(double);
    size_t off = (coefBytes + 255) & ~(size_t)255;
    double* coef = (double*)ws;
    int* minz = (int*)(ws + off);
    off += 256;
    float* sink = (float*)(ws + off);
    off += 8192;
    float4* gxa = (float4*)(ws + off);

    size_t shmem = (size_t)(7 * nf) * sizeof(double);
    spline_setup<<<1, 64, shmem, stream>>>(delay, raw, coef, minz, nf);
    eval_kernel<<<(nTot + 255) / 256, 256, 0, stream>>>(coef, gxa, minz, n, nTot, nf);
    scan_kernel<<<1, 128, 0, stream>>>(gxa, minz, exc, (float*)d_out, sink, n, burst);
}

// Round 15
// 150.859 us; speedup vs baseline: 1.9556x; 1.9556x over previous
//
#include <hip/hip_runtime.h>
#include <math.h>

// ---------------------------------------------------------------------------
// Phase 1: natural cubic spline coefficients, 3 channels, via PARALLEL
// CYCLIC REDUCTION (PCR) — replaces the serial Thomas solve whose 250
// LDS-round-trip iterations cost ~50us (round-14 post-mortem).
// System: T k = r, T = tridiag(1, [2,4,...,4,2], 1) (diag-dominant => PCR
// stable in f64). 256 threads, one equation per thread, 8 strides
// (1..128), guard-padded identity rows eliminate boundary branches.
// ---------------------------------------------------------------------------
#define OFF 128
__global__ void __launch_bounds__(256)
spline_setup(const float* __restrict__ delay_in,
             const float* __restrict__ raw,
             double* __restrict__ coef,
             int* __restrict__ minz,
             int nf) {
    __shared__ double xch[3 * 256];
    __shared__ double Aa[2][512], Ab[2][512], Ac[2][512];
    __shared__ double Ad0[2][512], Ad1[2][512], Ad2[2][512];

    const int tid = threadIdx.x;
    if (tid == 0) *minz = 0x7fffffff;

    // identity-init both ping-pong buffers (incl. guard zones)
    #pragma unroll
    for (int b = 0; b < 2; ++b)
        for (int i = tid; i < 512; i += 256) {
            Aa[b][i] = 0.0; Ab[b][i] = 1.0; Ac[b][i] = 0.0;
            Ad0[b][i] = 0.0; Ad1[b][i] = 0.0; Ad2[b][i] = 0.0;
        }

    if (tid < nf) {
        double s0 = 1.0 / (1.0 + exp(-(double)raw[2 * tid + 0]));
        double s1 = 1.0 / (1.0 + exp(-(double)raw[2 * tid + 1]));
        double ss = s0 + s1;
        xch[0 * 256 + tid] = (double)delay_in[tid];
        xch[1 * 256 + tid] = s0 / ss;
        xch[2 * 256 + tid] = s1 / ss;
    }
    __syncthreads();

    // row init into buffer 0
    if (tid < nf) {
        int i = tid;
        double hinv = (double)(nf - 1);
        Aa[0][OFF + i] = (i > 0) ? 1.0 : 0.0;
        Ac[0][OFF + i] = (i < nf - 1) ? 1.0 : 0.0;
        Ab[0][OFF + i] = (i == 0 || i == nf - 1) ? 2.0 : 4.0;
        #pragma unroll
        for (int ch = 0; ch < 3; ++ch) {
            const double* x = xch + ch * 256;
            double r = 0.0;
            if (i < nf - 1) r += 3.0 * hinv * (x[i + 1] - x[i]);
            if (i > 0)      r += 3.0 * hinv * (x[i] - x[i - 1]);
            if (ch == 0) Ad0[0][OFF + i] = r;
            else if (ch == 1) Ad1[0][OFF + i] = r;
            else Ad2[0][OFF + i] = r;
        }
    }
    __syncthreads();

    // PCR: strides 1,2,4,...,128 (nf<=256)
    int cur = 0;
    for (int s = 1; s < nf; s <<= 1) {
        int nxt = cur ^ 1;
        int ic = OFF + tid, im = ic - s, ip = ic + s;
        double ai = Aa[cur][ic], bi = Ab[cur][ic], ci = Ac[cur][ic];
        double bm = Ab[cur][im], bp = Ab[cur][ip];
        double alpha = -ai / bm;
        double gamma = -ci / bp;
        double na = alpha * Aa[cur][im];
        double nc = gamma * Ac[cur][ip];
        double nb = bi + alpha * Ac[cur][im] + gamma * Aa[cur][ip];
        double n0 = Ad0[cur][ic] + alpha * Ad0[cur][im] + gamma * Ad0[cur][ip];
        double n1 = Ad1[cur][ic] + alpha * Ad1[cur][im] + gamma * Ad1[cur][ip];
        double n2 = Ad2[cur][ic] + alpha * Ad2[cur][im] + gamma * Ad2[cur][ip];
        Aa[nxt][ic] = na; Ab[nxt][ic] = nb; Ac[nxt][ic] = nc;
        Ad0[nxt][ic] = n0; Ad1[nxt][ic] = n1; Ad2[nxt][ic] = n2;
        cur = nxt;
        __syncthreads();
    }

    // per-interval coefficients: thread i < nint handles all 3 channels
    int nint = nf - 1;
    double hinv = (double)(nf - 1);
    if (tid < nint) {
        int i = tid;
        double bI = Ab[cur][OFF + i], bI1 = Ab[cur][OFF + i + 1];
        double rbI = 1.0 / bI, rbI1 = 1.0 / bI1;
        #pragma unroll
        for (int ch = 0; ch < 3; ++ch) {
            double ki, ki1;
            if (ch == 0) { ki = Ad0[cur][OFF + i] * rbI; ki1 = Ad0[cur][OFF + i + 1] * rbI1; }
            else if (ch == 1) { ki = Ad1[cur][OFF + i] * rbI; ki1 = Ad1[cur][OFF + i + 1] * rbI1; }
            else { ki = Ad2[cur][OFF + i] * rbI; ki1 = Ad2[cur][OFF + i + 1] * rbI1; }
            const double* x = xch + ch * 256;
            double dx3 = 3.0 * (x[i + 1] - x[i]);
            double two_c   = (2.0 * dx3 * hinv - 4.0 * ki - 2.0 * ki1) * hinv;
            double three_d = (-2.0 * dx3 * hinv + 3.0 * (ki + ki1)) * hinv * hinv;
            double* C = coef + (size_t)(ch * nint + i) * 4;
            C[0] = x[i];
            C[1] = ki;
            C[2] = 0.5 * two_c;
            C[3] = three_d * (1.0 / 3.0);
        }
    }
}

// ---------------------------------------------------------------------------
// Phase 2: per-sample spline eval -> {g1, g2, g3, s3} one float4.
// s3 = (t - z - 3) & 2047. Global min z via one atomic per wave.
// Pads [n, nTot) with zeros.
// ---------------------------------------------------------------------------
__global__ void eval_kernel(const double* __restrict__ coef,
                            float4* __restrict__ gx,
                            int* __restrict__ minz,
                            int n, int nTot, int nf) {
    int j = blockIdx.x * blockDim.x + threadIdx.x;
    if (j >= nTot) return;
    if (j >= n) { gx[j] = make_float4(0.f, 0.f, 0.f, 0.f); return; }

    double u = (double)j / (double)(n - 1);
    double nfm1 = (double)(nf - 1);
    int idx = (int)(u * nfm1);
    if (idx > nf - 2) idx = nf - 2;
    if (idx < 0) idx = 0;
    double tknot = (double)idx / nfm1;
    if (u < tknot && idx > 0) {
        idx--; tknot = (double)idx / nfm1;
    } else {
        double tnext = (double)(idx + 1) / nfm1;
        if (u >= tnext && idx < nf - 2) { idx++; tknot = tnext; }
    }
    double f = u - tknot;

    int nint = nf - 1;
    const double* C0 = coef + (size_t)(0 * nint + idx) * 4;
    const double* C1 = coef + (size_t)(1 * nint + idx) * 4;
    const double* C2 = coef + (size_t)(2 * nint + idx) * 4;
    double dly = C0[0] + f * (C0[1] + f * (C0[2] + f * C0[3]));
    double b1d = C1[0] + f * (C1[1] + f * (C1[2] + f * C1[3]));
    double b2d = C2[0] + f * (C2[1] + f * (C2[2] + f * C2[3]));

    double zf = floor(dly);
    int z = (int)zf;
    float alfa = (float)(dly - zf);
    float b1 = (float)b1d, b2 = (float)b2d;
    float g1 = b1 * (1.0f - alfa);
    float g2 = b1 * alfa + b2 * (1.0f - alfa);
    float g3 = b2 * alfa;

    int s3 = (j - z - 3) & 2047;
    gx[j] = make_float4(g1, g2, g3, __uint_as_float((unsigned int)s3));

    int wmin = z;
    #pragma unroll
    for (int o = 32; o > 0; o >>= 1) wmin = min(wmin, __shfl_down(wmin, o, 64));
    if ((threadIdx.x & 63) == 0) atomicMin(minz, wmin);
}

// ---------------------------------------------------------------------------
// Phase 3: producer/consumer, FIXED D=64 (validated R13: 144cy/row = LDS
// round-trip floor). Group = 16 chunks = 1024 samples. Minimal row body:
// compile-time offsets only. Producer: 16 y-offload stores + 16
// global_load_lds (group g+2, 4-deep ring) + counted vmcnt(32); loads stay
// in flight across the raw s_barrier.
// ---------------------------------------------------------------------------
__global__ void __launch_bounds__(128, 1)
scan_kernel(const float4* __restrict__ gx,
            const int* __restrict__ minz,
            const float* __restrict__ exc,
            float* __restrict__ y,
            float* __restrict__ sink,
            int n, int burst) {
    __shared__ float buf[2052];          // 2048 circular + 2 shadow + pad
    __shared__ float excl[2048];
    __shared__ float4 ring[4 * 1024];    // 4 group-slots x 16 chunks x 64 = 64 KB

    const int tid = threadIdx.x;
    for (int i = tid; i < 2052; i += 128) buf[i] = 0.0f;
    for (int i = tid; i < 2048; i += 128) excl[i] = (i < burst) ? exc[i] : 0.0f;

    int mz = __builtin_amdgcn_readfirstlane(*minz);
    const int nFull = n >> 10;

#define GLL(gsrc, ldst)                                                       \
    __builtin_amdgcn_global_load_lds(                                         \
        (const __attribute__((address_space(1))) void*)(gsrc),                \
        (__attribute__((address_space(3))) void*)(ldst), 16, 0, 0)

    // ---------------- fallback (never taken for this data: mz ~ 100) -------
    if (mz < 63 || nFull < 2) {
        __syncthreads();
        if (tid < 64) {
            int Df = mz + 1;
            if (Df > 64) Df = 64;
            if (Df < 1) Df = 1;
            for (int base = 0; base < n; base += Df) {
                int t = base + tid;
                bool ok = (tid < Df) && (t < n);
                float4 q = ok ? gx[t] : make_float4(0.f, 0.f, 0.f, 0.f);
                unsigned u = __float_as_uint(q.w);
                float a3 = buf[u], a2 = buf[u + 1], a1 = buf[u + 2];
                float x = (t < burst) ? excl[t & 2047] : 0.0f;
                float y0 = fmaf(q.x, a1, x);
                y0 = fmaf(q.y, a2, y0);
                y0 = fmaf(q.z, a3, y0);
                if (ok) {
                    int w = t & 2047;
                    buf[w] = y0;
                    if (w < 2) buf[2048 + w] = y0;
                    y[t] = y0;
                }
            }
        }
        return;
    }

    // ---------------- prologue: producer fills groups 0,1 ------------------
    if (tid >= 64) {
        int lane = tid - 64;
        #pragma unroll
        for (int c = 0; c < 16; ++c)
            GLL(gx + (c << 6) + lane, &ring[(c << 6)]);
        #pragma unroll
        for (int c = 0; c < 16; ++c)
            GLL(gx + 1024 + (c << 6) + lane, &ring[1024 + (c << 6)]);
    }
    __syncthreads();   // full drain: groups 0,1 resident; buf/excl visible

    for (int g = 0; g < nFull; ++g) {
        if (tid >= 64) {
            // ---------------- producer ----------------
            int lane = tid - 64;
            int prevw = ((g - 1) & 1) << 10;       // buf window of group g-1
            int prev = (g - 1) << 10;
            float vals[16];
            #pragma unroll
            for (int k = 0; k < 16; ++k)
                vals[k] = buf[prevw + (k << 6) + lane];
            #pragma unroll
            for (int k = 0; k < 16; ++k) {
                int off = (k << 6) + lane;
                float* dst = (g > 0) ? (y + prev + off) : (sink + off);
                *dst = vals[k];                    // exactly 16 stores
            }
            int pb = (g + 2) << 10;
            int slot = (g + 2) & 3;
            #pragma unroll
            for (int c = 0; c < 16; ++c)
                GLL(gx + pb + (c << 6) + lane, &ring[(slot << 10) + (c << 6)]);
            // counted wait: drains prev group's 32 ops (incl. g+1's loads)
            asm volatile("s_waitcnt vmcnt(32)" ::: "memory");
        } else {
            // ---------------- consumer (pure LDS) ----------------
            const float4* Rp = ring + ((g & 3) << 10);
            int wb = ((g & 1) << 10) + tid;        // buf write base (c=0)
            int gb = g << 10;
            bool wx = (gb < burst);                // uniform; first 2 groups
            float4 q = Rp[tid];
            #pragma unroll
            for (int c = 0; c < 16; ++c) {
                float4 qn;
                if (c < 15) qn = Rp[((c + 1) << 6) + tid];
                unsigned u = __float_as_uint(q.w);
                float a3 = buf[u], a2 = buf[u + 1], a1 = buf[u + 2];
                float x = 0.0f;
                if (wx) {
                    int t = gb + (c << 6) + tid;
                    x = (t < burst) ? excl[t & 2047] : 0.0f;
                }
                float y0 = fmaf(q.x, a1, x);
                y0 = fmaf(q.y, a2, y0);
                y0 = fmaf(q.z, a3, y0);
                buf[wb + (c << 6)] = y0;
                if (c == 0 && (g & 1) == 0 && tid < 2) buf[2048 + tid] = y0;
                q = qn;
            }
        }
        // raw barrier: producer's g+2 loads stay in flight across it
        asm volatile("s_waitcnt lgkmcnt(0)" ::: "memory");
        __builtin_amdgcn_sched_barrier(0);
        __builtin_amdgcn_s_barrier();
        __builtin_amdgcn_sched_barrier(0);
    }

    __syncthreads();   // drain everything before epilogue

    if (tid >= 64) {
        // offload group nFull-1 (final in buf)
        int lane = tid - 64;
        int start = (nFull - 1) << 10;
        #pragma unroll
        for (int k = 0; k < 16; ++k) {
            int t = start + (k << 6) + lane;
            if (t < n) y[t] = buf[t & 2047];
        }
    } else {
        // tail samples [nFull<<10, n): direct-global, masked (empty when 1024|n)
        for (int base = nFull << 10; base < n; base += 64) {
            int t = base + tid;
            bool ok = (t < n);
            float4 q = ok ? gx[t] : make_float4(0.f, 0.f, 0.f, 0.f);
            unsigned u = __float_as_uint(q.w);
            float a3 = buf[u], a2 = buf[u + 1], a1 = buf[u + 2];
            float x = (t < burst) ? excl[t & 2047] : 0.0f;
            float y0 = fmaf(q.x, a1, x);
            y0 = fmaf(q.y, a2, y0);
            y0 = fmaf(q.z, a3, y0);
            if (ok) {
                int w = t & 2047;
                buf[w] = y0;
                if (w < 2) buf[2048 + w] = y0;
                y[t] = y0;
            }
        }
    }
#undef GLL
}

// ---------------------------------------------------------------------------
extern "C" void kernel_launch(void* const* d_in, const int* in_sizes, int n_in,
                              void* d_out, int out_size, void* d_ws, size_t ws_size,
                              hipStream_t stream) {
    const float* delay = (const float*)d_in[0];
    const float* raw   = (const float*)d_in[1];
    const float* exc   = (const float*)d_in[2];
    int nf = in_sizes[0];
    int burst = in_sizes[2];
    if (burst > 2048) burst = 2048;
    int n = out_size;
    int nTot = n + 4096;   // pad covers producer prefetch overshoot (2 groups)

    char* ws = (char*)d_ws;
    size_t coefBytes = (size_t)3 * (nf - 1) * 4 * sizeof(double);
    size_t off = (coefBytes + 255) & ~(size_t)255;
    double* coef = (double*)ws;
    int* minz = (int*)(ws + off);
    off += 256;
    float* sink = (float*)(ws + off);
    off += 4096;
    float4* gxa = (float4*)(ws + off);

    spline_setup<<<1, 256, 0, stream>>>(delay, raw, coef, minz, nf);
    eval_kernel<<<(nTot + 255) / 256, 256, 0, stream>>>(coef, gxa, minz, n, nTot, nf);
    scan_kernel<<<1, 128, 0, stream>>>(gxa, minz, exc, (float*)d_out, sink, n, burst);
}